// Round 7
// baseline (1023.430 us; speedup 1.0000x reference)
//
#include <hip/hip_runtime.h>

// ---------------------------------------------------------------------------
// GCN forward, fully fused layers (gather -> MFMA in one kernel).
//   P = dinv ⊙ activation (fp16) is the only inter-layer tensor.
//   per layer (one kernel, 64 dsts/block):
//     M[d] = fp16( dinv[d] * (sum_{s in N(d)} P[s] + P[d]) )   -> LDS
//     out  = M @ W + b   (f16 MFMA, W = hi + lo*2^-12 split)
//     P_next = dinv ⊙ relu(out)    (last layer: raw relu(out))
//   pool: mean over sorted batch ids, then 128->10 head.
// Output: y[512*10] ++ global_mean[512*128], fp32.
// ---------------------------------------------------------------------------

#define ATOMIC_ADD_F32(p, v) __hip_atomic_fetch_add((p), (v), __ATOMIC_RELAXED, __HIP_MEMORY_SCOPE_AGENT)

constexpr int NG = 512;   // NUM_GRAPHS
constexpr float LO_SCALE = 4096.f;      // 2^12
constexpr float LO_INV   = 1.f / 4096.f;

typedef _Float16 half8 __attribute__((ext_vector_type(8)));
typedef _Float16 half4 __attribute__((ext_vector_type(4)));
typedef float f32x4 __attribute__((ext_vector_type(4)));

// --- degree (XCD-partitioned histogram; deg = in-edge count, no self-loop) ---
__global__ __launch_bounds__(256) void k_deg_count_xcd(const int* __restrict__ dst,
                                                       int* __restrict__ deg,
                                                       int E, int N) {
    const int range = blockIdx.x & 7;
    const int chunk = blockIdx.x >> 3;
    const int nchunks = gridDim.x >> 3;
    const int csz = (E + nchunks - 1) / nchunks;
    const int lo = chunk * csz;
    const int hi = min(lo + csz, E);
    const int nr = N / 8;
    const int rlo = range * nr;
    const int rhi = (range == 7) ? N : rlo + nr;
    for (int i = lo + threadIdx.x; i < hi; i += 256) {
        int d = dst[i];
        if (d >= rlo && d < rhi) atomicAdd(&deg[d], 1);
    }
}

// --- exclusive scan of deg -> rowptr; dinv = rsqrt(deg+1) --------------------
__global__ __launch_bounds__(256) void k_scan_local(const int* __restrict__ deg,
                                                    int* __restrict__ rowptr,
                                                    int* __restrict__ partials,
                                                    float* __restrict__ dinv, int N) {
    __shared__ int s[256];
    int t = threadIdx.x;
    int i = blockIdx.x * 256 + t;
    int dg = (i < N) ? deg[i] : 0;
    if (i < N) dinv[i] = rsqrtf((float)(dg + 1));
    s[t] = dg;
    __syncthreads();
#pragma unroll
    for (int off = 1; off < 256; off <<= 1) {
        int add = (t >= off) ? s[t - off] : 0;
        __syncthreads();
        s[t] += add;
        __syncthreads();
    }
    if (i < N) rowptr[i] = s[t] - dg;
    if (t == 255) partials[blockIdx.x] = s[t];
}

__global__ __launch_bounds__(512) void k_scan_partials(int* __restrict__ partials, int nblk) {
    __shared__ int s[512];
    int t = threadIdx.x;
    int v = (t < nblk) ? partials[t] : 0;
    s[t] = v;
    __syncthreads();
#pragma unroll
    for (int off = 1; off < 512; off <<= 1) {
        int add = (t >= off) ? s[t - off] : 0;
        __syncthreads();
        s[t] += add;
        __syncthreads();
    }
    if (t < nblk) partials[t] = s[t] - v;
}

// also seeds cursor = rowptr
__global__ __launch_bounds__(256) void k_scan_apply(const int* __restrict__ deg,
                                                    int* __restrict__ rowptr,
                                                    int* __restrict__ cursor,
                                                    const int* __restrict__ partials, int N) {
    int i = blockIdx.x * 256 + threadIdx.x;
    if (i < N) {
        int r = rowptr[i] + partials[blockIdx.x];
        rowptr[i] = r;
        cursor[i] = r;
        if (i == N - 1) rowptr[N] = r + deg[i];
    }
}

// --- CSR fill, XCD-partitioned ------------------------------------------------
__global__ __launch_bounds__(256) void k_csr_fill_xcd(const int* __restrict__ src,
                                                      const int* __restrict__ dst,
                                                      int* __restrict__ cursor,
                                                      int* __restrict__ csr_src,
                                                      int E, int N) {
    const int range = blockIdx.x & 7;
    const int chunk = blockIdx.x >> 3;
    const int nchunks = gridDim.x >> 3;
    const int csz = (E + nchunks - 1) / nchunks;
    const int lo = chunk * csz;
    const int hi = min(lo + csz, E);
    const int nr = N / 8;
    const int rlo = range * nr;
    const int rhi = (range == 7) ? N : rlo + nr;
    for (int i = lo + threadIdx.x; i < hi; i += 256) {
        int d = dst[i];
        if (d >= rlo && d < rhi) {
            int pos = atomicAdd(&cursor[d], 1);
            csr_src[pos] = src[i];
        }
    }
}

// --- W prep: all 4 layers in one launch ----------------------------------------
struct WSplitArgs {
    const float* W[4];
    _Float16* Wth[4];
    _Float16* Wtl[4];
};
__global__ __launch_bounds__(256) void k_wsplit4(WSplitArgs a) {
    int idx = blockIdx.x * 256 + threadIdx.x;   // 4 * 16384 total
    int layer = idx >> 14;
    int e = idx & 16383;
    int k = e >> 7, c = e & 127;
    float w = a.W[layer][e];
    _Float16 hi = (_Float16)w;
    float lo = (w - (float)hi) * LO_SCALE;
    a.Wth[layer][c * 128 + k] = hi;
    a.Wtl[layer][c * 128 + k] = (_Float16)lo;
}

// --- X prep: P0 = dinv ⊙ X, fp32 -> fp16 ---------------------------------------
__global__ __launch_bounds__(256) void k_xscale(const float* __restrict__ X,
                                                const float* __restrict__ dinv,
                                                _Float16* __restrict__ P, int N) {
    int i = blockIdx.x * 256 + threadIdx.x;     // over N*32 float4 groups
    if (i >= N * 32) return;
    float dd = dinv[i >> 5];
    float4 v = ((const float4*)X)[i];
    half4 h = { (_Float16)(v.x * dd), (_Float16)(v.y * dd),
                (_Float16)(v.z * dd), (_Float16)(v.w * dd) };
    ((half4*)P)[i] = h;
}

// --- fused layer: gather into LDS, then MFMA ------------------------------------
// block = 256 threads = 4 waves, 64 dst rows per block.
// LDS M: 64 rows x 272 B (128 fp16 + 16 B pad -> conflict-free b128 reads).
__global__ __launch_bounds__(256) void k_layer(const int* __restrict__ csr_src,
                                               const int* __restrict__ rowptr,
                                               const float* __restrict__ dinv,
                                               const _Float16* __restrict__ P,
                                               const _Float16* __restrict__ Wth,
                                               const _Float16* __restrict__ Wtl,
                                               const float* __restrict__ bias,
                                               _Float16* __restrict__ Pout,
                                               int N, int last) {
    __shared__ char Ms[64 * 272];
    const int tid = threadIdx.x;
    const int wave = tid >> 6;
    const int lane = tid & 63;
    const int row0 = blockIdx.x * 64;
    const unsigned* Pu = (const unsigned*)P;

    union PK { unsigned u; _Float16 h[2]; };

    // ---- gather phase: wave handles 16 consecutive local rows
    for (int r = wave * 16; r < wave * 16 + 16; ++r) {
        int d = row0 + r;
        float ax = 0.f, ay = 0.f;
        if (d < N) {
            PK v; v.u = Pu[(size_t)d * 64 + lane];        // self term
            ax = (float)v.h[0]; ay = (float)v.h[1];
            int beg = rowptr[d], end = rowptr[d + 1];
            int j = beg;
            for (; j + 7 < end; j += 8) {
                int s[8]; PK t[8];
#pragma unroll
                for (int u = 0; u < 8; ++u) s[u] = csr_src[j + u];
#pragma unroll
                for (int u = 0; u < 8; ++u) t[u].u = Pu[(size_t)s[u] * 64 + lane];
#pragma unroll
                for (int u = 0; u < 8; ++u) { ax += (float)t[u].h[0]; ay += (float)t[u].h[1]; }
            }
            for (; j < end; ++j) {
                PK t; t.u = Pu[(size_t)csr_src[j] * 64 + lane];
                ax += (float)t.h[0]; ay += (float)t.h[1];
            }
            float dd = dinv[d];
            ax *= dd; ay *= dd;
        }
        PK o; o.h[0] = (_Float16)ax; o.h[1] = (_Float16)ay;
        *(unsigned*)(Ms + r * 272 + lane * 4) = o.u;
    }
    __syncthreads();

    // ---- MFMA phase: M (LDS) @ W (global, L2-hot)
    const int wrow = wave & 1;
    const int wcol = wave >> 1;
    const int lr = lane & 15;
    const int q = lane >> 4;          // 0..3
    const int c_base = wcol * 64;

    f32x4 acch[2][4], accl[2][4];
#pragma unroll
    for (int rt = 0; rt < 2; ++rt)
#pragma unroll
        for (int ct = 0; ct < 4; ++ct) {
            acch[rt][ct] = (f32x4){0.f, 0.f, 0.f, 0.f};
            accl[rt][ct] = (f32x4){0.f, 0.f, 0.f, 0.f};
        }

#pragma unroll
    for (int ks = 0; ks < 4; ++ks) {
        half8 bh[4], bl[4];
#pragma unroll
        for (int ct = 0; ct < 4; ++ct) {
            size_t off = (size_t)(c_base + ct * 16 + lr) * 128 + ks * 32 + q * 8;
            bh[ct] = *(const half8*)(Wth + off);
            bl[ct] = *(const half8*)(Wtl + off);
        }
        half8 a[2];
#pragma unroll
        for (int rt = 0; rt < 2; ++rt) {
            int lrow = wrow * 32 + rt * 16 + lr;
            a[rt] = *(const half8*)(Ms + lrow * 272 + ks * 64 + q * 16);
        }
#pragma unroll
        for (int rt = 0; rt < 2; ++rt)
#pragma unroll
            for (int ct = 0; ct < 4; ++ct) {
                acch[rt][ct] = __builtin_amdgcn_mfma_f32_16x16x32_f16(a[rt], bh[ct], acch[rt][ct], 0, 0, 0);
                accl[rt][ct] = __builtin_amdgcn_mfma_f32_16x16x32_f16(a[rt], bl[ct], accl[rt][ct], 0, 0, 0);
            }
    }

    // ---- epilogue: +bias, relu, (x dinv unless last), store fp16
    float bcol[4];
#pragma unroll
    for (int ct = 0; ct < 4; ++ct) bcol[ct] = bias[c_base + ct * 16 + lr];

#pragma unroll
    for (int rt = 0; rt < 2; ++rt) {
        int r0 = row0 + wrow * 32 + rt * 16 + q * 4;
        float dv[4];
#pragma unroll
        for (int j = 0; j < 4; ++j) {
            int r = r0 + j;
            dv[j] = (!last && r < N) ? dinv[r] : 1.f;
        }
#pragma unroll
        for (int ct = 0; ct < 4; ++ct) {
            int col = c_base + ct * 16 + lr;
#pragma unroll
            for (int j = 0; j < 4; ++j) {
                int r = r0 + j;
                if (r < N) {
                    float v = fmaf(accl[rt][ct][j], LO_INV, acch[rt][ct][j]) + bcol[ct];
                    v = fmaxf(v, 0.f);
                    Pout[(size_t)r * 128 + col] = (_Float16)(v * dv[j]);
                }
            }
        }
    }
}

// --- pool: pooled[g] += A[i] (activations, bias+relu applied), batch sorted ----
__global__ __launch_bounds__(128) void k_pool(const _Float16* __restrict__ A,
                                              const int* __restrict__ batch,
                                              float* __restrict__ pooled,
                                              float* __restrict__ counts, int N) {
    int k = threadIdx.x;
    int i0 = blockIdx.x * 64;
    if (i0 >= N) return;
    int iend = min(i0 + 64, N);
    float acc = 0.f;
    int cnt = 0;
    int cur = batch[i0];
    for (int i = i0; i < iend; ++i) {
        int g = batch[i];
        if (g != cur) {
            ATOMIC_ADD_F32(&pooled[cur * 128 + k], acc);
            if (k == 0) ATOMIC_ADD_F32(&counts[cur], (float)cnt);
            acc = 0.f; cnt = 0; cur = g;
        }
        acc += (float)A[(size_t)i * 128 + k];
        cnt++;
    }
    ATOMIC_ADD_F32(&pooled[cur * 128 + k], acc);
    if (k == 0) ATOMIC_ADD_F32(&counts[cur], (float)cnt);
}

// --- finalize: global_mean + head ------------------------------------------------
__global__ __launch_bounds__(128) void k_finalize(const float* __restrict__ pooled,
                                                  const float* __restrict__ counts,
                                                  const float* __restrict__ Wl,
                                                  const float* __restrict__ bl,
                                                  float* __restrict__ out) {
    int g = blockIdx.x;
    int t = threadIdx.x;
    __shared__ float m[128];
    float c = fmaxf(counts[g], 1.f);
    float mean = pooled[g * 128 + t] / c;
    out[NG * 10 + g * 128 + t] = mean;
    m[t] = mean;
    __syncthreads();
    if (t < 10) {
        float acc = bl[t];
#pragma unroll 16
        for (int k = 0; k < 128; ++k) acc = fmaf(m[k], Wl[k * 10 + t], acc);
        out[g * 10 + t] = acc;
    }
}

// ---------------------------------------------------------------------------
extern "C" void kernel_launch(void* const* d_in, const int* in_sizes, int n_in,
                              void* d_out, int out_size, void* d_ws, size_t ws_size,
                              hipStream_t stream) {
    const float* x     = (const float*)d_in[0];
    const int*   ei    = (const int*)d_in[1];
    const int*   batch = (const int*)d_in[2];
    const float* Wt[4] = { (const float*)d_in[3], (const float*)d_in[5],
                           (const float*)d_in[7], (const float*)d_in[9] };
    const float* bt[4] = { (const float*)d_in[4], (const float*)d_in[6],
                           (const float*)d_in[8], (const float*)d_in[10] };
    const float* Wl = (const float*)d_in[11];
    const float* bl = (const float*)d_in[12];
    float* out = (float*)d_out;

    const int N = in_sizes[0] / 128;
    const int E = in_sizes[1] / 2;
    const int* src = ei;
    const int* dst = ei + E;

    // workspace layout
    char* p = (char*)d_ws;
    _Float16* Pa    = (_Float16*)p;  p += (size_t)N * 128 * 2;
    _Float16* Pb    = (_Float16*)p;  p += (size_t)N * 128 * 2;
    float* dinv     = (float*)p;     p += (size_t)N * 4;
    int*   deg      = (int*)p;       p += (size_t)N * 4;
    int*   rowptr   = (int*)p;       p += (size_t)(N + 1) * 4;
    int*   cursor   = (int*)p;       p += (size_t)N * 4;
    int*   csr_src  = (int*)p;       p += (size_t)E * 4;
    int*   partials = (int*)p;       p += 512 * 4;
    float* pooled   = (float*)p;     p += (size_t)NG * 128 * 4;
    float* counts   = (float*)p;     p += (size_t)NG * 4;
    _Float16* Wsp   = (_Float16*)p;  p += 4 * 2 * 128 * 128 * 2;

    const int nblk = (N + 255) / 256;

    // degrees (edge count only; self-loop folded into dinv)
    hipMemsetAsync(deg, 0, (size_t)N * 4, stream);
    k_deg_count_xcd<<<2048, 256, 0, stream>>>(dst, deg, E, N);

    // CSR build (by dst); scan fused with dinv + cursor seed
    k_scan_local<<<nblk, 256, 0, stream>>>(deg, rowptr, partials, dinv, N);
    k_scan_partials<<<1, 512, 0, stream>>>(partials, nblk);
    k_scan_apply<<<nblk, 256, 0, stream>>>(deg, rowptr, cursor, partials, N);
    k_csr_fill_xcd<<<2048, 256, 0, stream>>>(src, dst, cursor, csr_src, E, N);

    // weight splits (one launch) + P0 = dinv * X
    WSplitArgs wa;
    _Float16* Wth[4]; _Float16* Wtl[4];
    for (int l = 0; l < 4; ++l) {
        Wth[l] = Wsp + (size_t)l * 2 * 16384;
        Wtl[l] = Wth[l] + 16384;
        wa.W[l] = Wt[l];
        wa.Wth[l] = Wth[l];
        wa.Wtl[l] = Wtl[l];
    }
    k_wsplit4<<<256, 256, 0, stream>>>(wa);
    k_xscale<<<(N * 32 + 255) / 256, 256, 0, stream>>>(x, dinv, Pa, N);

    // fused layers
    const int layer_blocks = (N + 63) / 64;
    _Float16* pin = Pa;
    _Float16* pout = Pb;
    for (int l = 0; l < 4; ++l) {
        k_layer<<<layer_blocks, 256, 0, stream>>>(csr_src, rowptr, dinv, pin,
                                                  Wth[l], Wtl[l], bt[l], pout,
                                                  N, (l == 3) ? 1 : 0);
        _Float16* tmp = pin; pin = pout; pout = tmp;
    }
    // final activations are in pin after the swap

    // pool + head
    hipMemsetAsync(pooled, 0, (size_t)(NG * 128 + NG) * 4, stream);
    k_pool<<<(N + 63) / 64, 128, 0, stream>>>(pin, batch, pooled, counts, N);
    k_finalize<<<NG, 128, 0, stream>>>(pooled, counts, Wl, bl, out);
}